// Round 2
// baseline (215.764 us; speedup 1.0000x reference)
//
#include <hip/hip_runtime.h>
#include <stdint.h>

using u16 = unsigned short;
using u32 = unsigned int;
using bf16x8 = __bf16 __attribute__((ext_vector_type(8)));
using f32x4  = float __attribute__((ext_vector_type(4)));

__device__ __forceinline__ float bflo(u32 u){ return __uint_as_float(u << 16); }
__device__ __forceinline__ float bfhi(u32 u){ return __uint_as_float(u & 0xffff0000u); }
__device__ __forceinline__ u16 f2bf(float f){
  u32 u = __float_as_uint(f);
  u += 0x7fffu + ((u >> 16) & 1u);
  return (u16)(u >> 16);
}
__device__ __forceinline__ u32 pk2(float a, float b){
  return (u32)f2bf(a) | ((u32)f2bf(b) << 16);
}
__device__ __forceinline__ void gload16(const void* g, void* l){
  __builtin_amdgcn_global_load_lds(
      (const __attribute__((address_space(1))) void*)(uintptr_t)(g),
      (__attribute__((address_space(3))) void*)(uintptr_t)(l), 16, 0, 0);
}

// ---------------- weight transpose + bf16 cast ----------------
__global__ __launch_bounds__(256) void transw_k(const float* __restrict__ Win,
                                                const float* __restrict__ Wout,
                                                u16* __restrict__ WinT,
                                                u16* __restrict__ WoutT){
  __shared__ float tile[32][33];
  const float* src = blockIdx.z ? Wout : Win;
  u16* dst = blockIdx.z ? WoutT : WinT;
  int tx = threadIdx.x & 31, ty = threadIdx.x >> 5;
  int c0 = blockIdx.x * 32, r0 = blockIdx.y * 32;
#pragma unroll
  for (int i = 0; i < 4; ++i)
    tile[ty + i*8][tx] = src[(size_t)(r0 + ty + i*8)*512 + c0 + tx];
  __syncthreads();
#pragma unroll
  for (int i = 0; i < 4; ++i)
    dst[(size_t)(c0 + ty + i*8)*512 + r0 + tx] = f2bf(tile[tx][ty + i*8]);
}

// ---------------- per-row LayerNorm stats (mu, rstd) ----------------
__global__ __launch_bounds__(256) void musig_k(const float* __restrict__ q,
                                               const float* __restrict__ k,
                                               const float* __restrict__ v,
                                               float* __restrict__ musig){
  int row = blockIdx.x * 4 + (threadIdx.x >> 6);
  int l = threadIdx.x & 63;
  const float* x = (row < 16384) ? q : (row < 32768) ? k : v;
  int r = row & 16383;
  const float4* p = (const float4*)(x + (size_t)r * 512) + l*2;
  float4 a = p[0], c = p[1];
  float sum = ((a.x+a.y)+(a.z+a.w)) + ((c.x+c.y)+(c.z+c.w));
  float ss  = ((a.x*a.x+a.y*a.y)+(a.z*a.z+a.w*a.w)) + ((c.x*c.x+c.y*c.y)+(c.z*c.z+c.w*c.w));
#pragma unroll
  for (int off = 32; off; off >>= 1){
    sum += __shfl_xor(sum, off);
    ss  += __shfl_xor(ss,  off);
  }
  if (l == 0){
    float mu = sum * (1.f/512.f);
    float var = ss * (1.f/512.f) - mu*mu;
    musig[2*row]   = mu;
    musig[2*row+1] = rsqrtf(var + 1e-5f);
  }
}

// ---------------- bf16 MFMA GEMM, 128x128 tile, BK=64 ----------------
// MODE 0: A = fp32 x with fused LayerNorm (musig,lnw,lnb), C = bf16
// MODE 1: A = bf16, C = fp32 + bias
template<int MODE>
__global__ __launch_bounds__(256) void gemm_k(
    const float* __restrict__ Af, const u16* __restrict__ Ab,
    const u16* __restrict__ Bt,          // [512][512] bf16, pre-transposed
    u16* __restrict__ Cb, float* __restrict__ Cf,
    const float* __restrict__ musig,     // [M][2]
    const float* __restrict__ lnw, const float* __restrict__ lnb,
    const float* __restrict__ bias){
  __shared__ __align__(16) char sA[128*128];
  __shared__ __align__(16) char sB[128*128];
  const int t = threadIdx.x, w = t >> 6, l = t & 63;
  const int wr = w >> 1, wc = w & 1;
  const int lr = l & 15, lg = l >> 4;
  const int row0 = blockIdx.x * 128, col0 = blockIdx.y * 128;
  f32x4 acc[4][4] = {};

  for (int kt = 0; kt < 8; ++kt){
    __syncthreads();
    // stage B via global_load_lds (source pre-swizzled, LDS linear)
#pragma unroll
    for (int ii = 0; ii < 4; ++ii){
      int c = ii*256 + t, r = c >> 3, k8 = c & 7;
      const char* src = (const char*)Bt + ((size_t)(col0 + r) << 10) + kt*128
                        + ((k8*16) ^ ((r & 7) << 4));
      gload16(src, sB + ii*4096 + w*1024);
    }
    if (MODE == 0){
      // reg-stage A: fp32 load -> LayerNorm -> bf16 -> swizzled LDS write
#pragma unroll
      for (int ii = 0; ii < 4; ++ii){
        int c = ii*256 + t, r = c >> 3, k8 = c & 7;
        int rg = row0 + r;
        const float* sp = Af + ((size_t)rg << 9) + kt*64 + k8*8;
        float4 x0 = *(const float4*)sp;
        float4 x1 = *(const float4*)(sp + 4);
        float mu = musig[2*rg], rs = musig[2*rg + 1];
        const float* wp = lnw + kt*64 + k8*8;
        const float* bp = lnb + kt*64 + k8*8;
        float4 w0 = *(const float4*)wp, w1 = *(const float4*)(wp + 4);
        float4 b0 = *(const float4*)bp, b1 = *(const float4*)(bp + 4);
        uint4 pk;
        pk.x = pk2((x0.x-mu)*rs*w0.x + b0.x, (x0.y-mu)*rs*w0.y + b0.y);
        pk.y = pk2((x0.z-mu)*rs*w0.z + b0.z, (x0.w-mu)*rs*w0.w + b0.w);
        pk.z = pk2((x1.x-mu)*rs*w1.x + b1.x, (x1.y-mu)*rs*w1.y + b1.y);
        pk.w = pk2((x1.z-mu)*rs*w1.z + b1.z, (x1.w-mu)*rs*w1.w + b1.w);
        *(uint4*)(sA + r*128 + ((k8*16) ^ ((r & 7) << 4))) = pk;
      }
    } else {
#pragma unroll
      for (int ii = 0; ii < 4; ++ii){
        int c = ii*256 + t, r = c >> 3, k8 = c & 7;
        const char* src = (const char*)Ab + ((size_t)(row0 + r) << 10) + kt*128
                          + ((k8*16) ^ ((r & 7) << 4));
        gload16(src, sA + ii*4096 + w*1024);
      }
    }
    __syncthreads();
#pragma unroll
    for (int kk = 0; kk < 2; ++kk){
      bf16x8 af[4], bfg[4];
#pragma unroll
      for (int m = 0; m < 4; ++m){
        int r = wr*64 + m*16 + lr;
        af[m] = *(const bf16x8*)(sA + r*128 + ((kk*64 + lg*16) ^ ((lr & 7) << 4)));
      }
#pragma unroll
      for (int n = 0; n < 4; ++n){
        int r = wc*64 + n*16 + lr;
        bfg[n] = *(const bf16x8*)(sB + r*128 + ((kk*64 + lg*16) ^ ((lr & 7) << 4)));
      }
#pragma unroll
      for (int m = 0; m < 4; ++m)
#pragma unroll
        for (int n = 0; n < 4; ++n)
          acc[m][n] = __builtin_amdgcn_mfma_f32_16x16x32_bf16(af[m], bfg[n], acc[m][n], 0, 0, 0);
    }
  }
  // epilogue: D row = (lane>>4)*4 + q, col = lane&15
#pragma unroll
  for (int m = 0; m < 4; ++m){
#pragma unroll
    for (int q = 0; q < 4; ++q){
      int r = row0 + wr*64 + m*16 + lg*4 + q;
#pragma unroll
      for (int n = 0; n < 4; ++n){
        int cc = col0 + wc*64 + n*16 + lr;
        float v = acc[m][n][q];
        if (MODE == 0) Cb[(size_t)r*512 + cc] = f2bf(v);
        else           Cf[(size_t)r*512 + cc] = v + bias[cc];
      }
    }
  }
}

// ---------------- attention: per (h,b), factored rank-64 form ----------------
__global__ __launch_bounds__(512) void attn_k(
    const u16* __restrict__ f,   // [3][16384][512] bf16 (q,k,v projections)
    u16* __restrict__ ao,        // [16384][512] bf16
    const float* __restrict__ cwr, const float* __restrict__ vwr){
  constexpr int SQ_OFF = 65536;              // sV (64K linear) then sQp [512][66 bf16]
  constexpr int ST_OFF = 65536 + 67584;      // sStat f32[3][512]
  constexpr int SP_OFF = ST_OFF + 6144;      // sPart f32[8][128]
  constexpr int SS_OFF = SP_OFF + 4096;      // sS f32[128]
  __shared__ __align__(16) char smem[SS_OFF + 512];

  const int t = threadIdx.x, w = t >> 6, l = t & 63;
  const int h = blockIdx.x & 7, b = blockIdx.x >> 3;
  const size_t FB = (size_t)16384 * 512 * 2;
  const char* fq = (const char*)f + ((size_t)b*512*512 + h*64) * 2;
  const char* fk = fq + FB;
  const char* fv = fq + 2*FB;
  char* sK = smem;
  char* sV = smem + SQ_OFF;
  float* sStat = (float*)(smem + ST_OFF);
  float* sPart = (float*)(smem + SP_OFF);
  float* sS    = (float*)(smem + SS_OFF);

  // stage K,V: [512][64] bf16, linear
#pragma unroll
  for (int ii = 0; ii < 8; ++ii){
    int c = ii*512 + t, m = c >> 3, k8 = c & 7;
    gload16(fk + (size_t)m*1024 + k8*16, sK + ii*8192 + w*1024);
    gload16(fv + (size_t)m*1024 + k8*16, sV + ii*8192 + w*1024);
  }
  __syncthreads();

  // k-stats: row m = t -> 1/||k||, mean, var(ddof=1)
  {
    float sum = 0.f, ss = 0.f;
#pragma unroll
    for (int c8 = 0; c8 < 8; ++c8){
      uint4 u = *(const uint4*)(sK + t*128 + c8*16);
      float a0=bflo(u.x),a1=bfhi(u.x),a2=bflo(u.y),a3=bfhi(u.y);
      float a4=bflo(u.z),a5=bfhi(u.z),a6=bflo(u.w),a7=bfhi(u.w);
      sum += ((a0+a1)+(a2+a3)) + ((a4+a5)+(a6+a7));
      ss  += ((a0*a0+a1*a1)+(a2*a2+a3*a3)) + ((a4*a4+a5*a5)+(a6*a6+a7*a7));
    }
    float mk = sum * 0.015625f;
    sStat[t]        = rsqrtf(ss);
    sStat[512 + t]  = mk;
    sStat[1024 + t] = (ss - 64.f*mk*mk) * (1.f/63.f);
  }
  __syncthreads();

  // phase 1: M1 = (K/kn)^T V, M2 = K^T V ; thread owns 4(i) x 2(j)
  const int i0 = (t & 15) << 2;
  const int j0 = (t >> 4) << 1;
  float m1a[4][2] = {}, m2a[4][2] = {};
#pragma unroll 4
  for (int m = 0; m < 512; ++m){
    float kin = sStat[m];
    uint2 ku = *(const uint2*)(sK + m*128 + i0*2);
    u32   vu = *(const u32*) (sV + m*128 + j0*2);
    float v0 = bflo(vu), v1 = bfhi(vu);
    float k0 = bflo(ku.x), k1 = bfhi(ku.x), k2 = bflo(ku.y), k3 = bfhi(ku.y);
    m2a[0][0] += k0*v0; m2a[0][1] += k0*v1;
    m2a[1][0] += k1*v0; m2a[1][1] += k1*v1;
    m2a[2][0] += k2*v0; m2a[2][1] += k2*v1;
    m2a[3][0] += k3*v0; m2a[3][1] += k3*v1;
    float s0 = k0*kin, s1 = k1*kin, s2 = k2*kin, s3 = k3*kin;
    m1a[0][0] += s0*v0; m1a[0][1] += s0*v1;
    m1a[1][0] += s1*v0; m1a[1][1] += s1*v1;
    m1a[2][0] += s2*v0; m1a[2][1] += s2*v1;
    m1a[3][0] += s3*v0; m1a[3][1] += s3*v1;
  }
  __syncthreads();   // sK free (M goes there); sV still live for sPart

  // write M1,M2 (f32 [2][64][64]) over sK region
  float* sM = (float*)sK;
#pragma unroll
  for (int ii = 0; ii < 4; ++ii){
    sM[(i0+ii)*64 + j0]          = m1a[ii][0];
    sM[(i0+ii)*64 + j0 + 1]      = m1a[ii][1];
    sM[4096 + (i0+ii)*64 + j0]     = m2a[ii][0];
    sM[4096 + (i0+ii)*64 + j0 + 1] = m2a[ii][1];
  }

  // s1/s2 partials: wave w covers m in [w*64, w*64+64), lane l -> j=l
  {
    float p1 = 0.f, p2 = 0.f;
#pragma unroll 8
    for (int mm = 0; mm < 64; ++mm){
      int m = (w << 6) + mm;
      float vv = __uint_as_float((u32)(*(const u16*)(sV + m*128 + l*2)) << 16);
      p1 += sStat[512 + m]*vv;
      p2 += sStat[1024 + m]*vv;
    }
    sPart[w*128 + l]      = p1;
    sPart[w*128 + 64 + l] = p2;
  }
  __syncthreads();   // sV free now

  // stage Q over sV region, padded stride 132B (bank-conflict-free row reads)
  char* sQ = sV;
#pragma unroll
  for (int ii = 0; ii < 8; ++ii){
    int c = ii*512 + t, m = c >> 3, k8 = c & 7;
    uint4 u = *(const uint4*)(fq + (size_t)m*1024 + k8*16);
    char* dp = sQ + m*132 + k8*16;
    *(u32*)(dp)      = u.x;
    *(u32*)(dp + 4)  = u.y;
    *(u32*)(dp + 8)  = u.z;
    *(u32*)(dp + 12) = u.w;
  }
  if (t < 128){
    float s = 0.f;
#pragma unroll
    for (int ww = 0; ww < 8; ++ww) s += sPart[ww*128 + t];
    sS[t] = s;
  }
  __syncthreads();

  // phase 2: row n = t. out = a*(q M1) + b*(q M2) + c*s1 + e*s2
  // q-row stats over FULL 64 elements = 32 u32 words (128 bytes)
  float sum = 0.f, ss = 0.f;
#pragma unroll
  for (int c = 0; c < 32; ++c){
    u32 u = *(const u32*)(sQ + t*132 + c*4);
    float a0 = bflo(u), a1 = bfhi(u);
    sum += a0 + a1; ss += a0*a0 + a1*a1;
  }
  float mq = sum * 0.015625f;
  float qv = (ss - 64.f*mq*mq) * (1.f/63.f);
  float cwv = 1.f/(1.f + __expf(-*cwr));
  float vwv = 1.f/(1.f + __expf(-*vwr));
  float cosw = 1.f - cwv - vwv;
  float aSc = cosw * rsqrtf(ss);
  float bSc = cwv * 0.015625f;
  float cSc = -cwv * mq;
  float eSc = vwv * 0.015625f * qv;

  const float* M1 = (const float*)smem;
  const float* M2 = M1 + 4096;
  float acc[64];
#pragma unroll
  for (int j = 0; j < 64; ++j) acc[j] = 0.f;
  for (int i = 0; i < 64; ++i){
    float qi = __uint_as_float((u32)(*(const u16*)(sQ + t*132 + i*2)) << 16);
    float qa = aSc * qi, qb = bSc * qi;
#pragma unroll
    for (int j = 0; j < 64; j += 4){
      float4 r1 = *(const float4*)(M1 + i*64 + j);
      float4 r2 = *(const float4*)(M2 + i*64 + j);
      acc[j]   += qa*r1.x + qb*r2.x;
      acc[j+1] += qa*r1.y + qb*r2.y;
      acc[j+2] += qa*r1.z + qb*r2.z;
      acc[j+3] += qa*r1.w + qb*r2.w;
    }
  }
  char* op = (char*)ao + ((size_t)(b*512 + t)*512 + h*64) * 2;
#pragma unroll
  for (int j = 0; j < 64; j += 8){
    uint4 pk;
    pk.x = pk2(acc[j]   + cSc*sS[j]   + eSc*sS[64+j],
               acc[j+1] + cSc*sS[j+1] + eSc*sS[64+j+1]);
    pk.y = pk2(acc[j+2] + cSc*sS[j+2] + eSc*sS[64+j+2],
               acc[j+3] + cSc*sS[j+3] + eSc*sS[64+j+3]);
    pk.z = pk2(acc[j+4] + cSc*sS[j+4] + eSc*sS[64+j+4],
               acc[j+5] + cSc*sS[j+5] + eSc*sS[64+j+5]);
    pk.w = pk2(acc[j+6] + cSc*sS[j+6] + eSc*sS[64+j+6],
               acc[j+7] + cSc*sS[j+7] + eSc*sS[64+j+7]);
    *(uint4*)(op + j*2) = pk;
  }
}

// ---------------- launch ----------------
extern "C" void kernel_launch(void* const* d_in, const int* in_sizes, int n_in,
                              void* d_out, int out_size, void* d_ws, size_t ws_size,
                              hipStream_t stream){
  const float* q    = (const float*)d_in[0];
  const float* k    = (const float*)d_in[1];
  const float* v    = (const float*)d_in[2];
  const float* lnw  = (const float*)d_in[3];
  const float* lnb  = (const float*)d_in[4];
  const float* Win  = (const float*)d_in[5];
  const float* Wout = (const float*)d_in[6];
  const float* bout = (const float*)d_in[7];
  const float* cwr  = (const float*)d_in[8];
  const float* vwr  = (const float*)d_in[9];

  char* ws = (char*)d_ws;
  const size_t FB = (size_t)16384 * 512 * 2;   // one bf16 [16384][512] buffer
  u16*   f     = (u16*)(ws);                    // 3*FB
  u16*   ao    = (u16*)(ws + 3*FB);             // FB
  float* musig = (float*)(ws + 4*FB);           // 49152*2*4 = 393216
  u16*   WinT  = (u16*)(ws + 4*FB + 393216);    // 524288
  u16*   WoutT = (u16*)(ws + 4*FB + 393216 + 524288);

  transw_k<<<dim3(16,16,2), 256, 0, stream>>>(Win, Wout, WinT, WoutT);
  musig_k<<<12288, 256, 0, stream>>>(q, k, v, musig);

  const float* xs[3] = {q, k, v};
  for (int i = 0; i < 3; ++i){
    gemm_k<0><<<dim3(128,4), 256, 0, stream>>>(
        xs[i], nullptr, WinT, f + (size_t)i*16384*512, nullptr,
        musig + (size_t)i*16384*2, lnw, lnb, nullptr);
  }
  attn_k<<<256, 512, 0, stream>>>(f, ao, cwr, vwr);
  gemm_k<1><<<dim3(128,4), 256, 0, stream>>>(
      nullptr, ao, WoutT, nullptr, (float*)d_out,
      nullptr, nullptr, nullptr, bout);
}

// Round 3
// 123.345 us; speedup vs baseline: 1.7493x; 1.7493x over previous
//
#include <hip/hip_runtime.h>
#include <stdint.h>

using u16 = unsigned short;
using u32 = unsigned int;
using bf16x8 = __bf16 __attribute__((ext_vector_type(8)));
using f32x4  = float __attribute__((ext_vector_type(4)));

__device__ __forceinline__ float bflo(u32 u){ return __uint_as_float(u << 16); }
__device__ __forceinline__ float bfhi(u32 u){ return __uint_as_float(u & 0xffff0000u); }
__device__ __forceinline__ u16 f2bf(float f){
  u32 u = __float_as_uint(f);
  u += 0x7fffu + ((u >> 16) & 1u);
  return (u16)(u >> 16);
}
__device__ __forceinline__ u32 pk2(float a, float b){
  return (u32)f2bf(a) | ((u32)f2bf(b) << 16);
}
__device__ __forceinline__ void gload16(const void* g, void* l){
  __builtin_amdgcn_global_load_lds(
      (const __attribute__((address_space(1))) void*)(uintptr_t)(g),
      (__attribute__((address_space(3))) void*)(uintptr_t)(l), 16, 0, 0);
}

// ---------------- weight transpose + bf16 cast ----------------
__global__ __launch_bounds__(256) void transw_k(const float* __restrict__ Win,
                                                const float* __restrict__ Wout,
                                                u16* __restrict__ WinT,
                                                u16* __restrict__ WoutT){
  __shared__ float tile[32][33];
  const float* src = blockIdx.z ? Wout : Win;
  u16* dst = blockIdx.z ? WoutT : WinT;
  int tx = threadIdx.x & 31, ty = threadIdx.x >> 5;
  int c0 = blockIdx.x * 32, r0 = blockIdx.y * 32;
#pragma unroll
  for (int i = 0; i < 4; ++i)
    tile[ty + i*8][tx] = src[(size_t)(r0 + ty + i*8)*512 + c0 + tx];
  __syncthreads();
#pragma unroll
  for (int i = 0; i < 4; ++i)
    dst[(size_t)(c0 + ty + i*8)*512 + r0 + tx] = f2bf(tile[tx][ty + i*8]);
}

// ---------------- fused LayerNorm stats + apply + bf16 cast ----------------
__global__ __launch_bounds__(256) void lnx_k(const float* __restrict__ q,
                                             const float* __restrict__ k,
                                             const float* __restrict__ v,
                                             const float* __restrict__ lnw,
                                             const float* __restrict__ lnb,
                                             u16* __restrict__ xnq,
                                             u16* __restrict__ xnk,
                                             u16* __restrict__ xnv){
  int row = blockIdx.x * 4 + (threadIdx.x >> 6);
  int l = threadIdx.x & 63;
  const float* x = (row < 16384) ? q : (row < 32768) ? k : v;
  u16* xo = (row < 16384) ? xnq : (row < 32768) ? xnk : xnv;
  int r = row & 16383;
  const float* rp = x + (size_t)r * 512 + l*8;
  float4 a = *(const float4*)rp, c = *(const float4*)(rp + 4);
  float sum = ((a.x+a.y)+(a.z+a.w)) + ((c.x+c.y)+(c.z+c.w));
  float ss  = ((a.x*a.x+a.y*a.y)+(a.z*a.z+a.w*a.w)) + ((c.x*c.x+c.y*c.y)+(c.z*c.z+c.w*c.w));
#pragma unroll
  for (int off = 32; off; off >>= 1){
    sum += __shfl_xor(sum, off);
    ss  += __shfl_xor(ss,  off);
  }
  float mu = sum * (1.f/512.f);
  float rs = rsqrtf(ss * (1.f/512.f) - mu*mu + 1e-5f);
  float4 w0 = *(const float4*)(lnw + l*8), w1 = *(const float4*)(lnw + l*8 + 4);
  float4 b0 = *(const float4*)(lnb + l*8), b1 = *(const float4*)(lnb + l*8 + 4);
  uint4 pk;
  pk.x = pk2((a.x-mu)*rs*w0.x + b0.x, (a.y-mu)*rs*w0.y + b0.y);
  pk.y = pk2((a.z-mu)*rs*w0.z + b0.z, (a.w-mu)*rs*w0.w + b0.w);
  pk.z = pk2((c.x-mu)*rs*w1.x + b1.x, (c.y-mu)*rs*w1.y + b1.y);
  pk.w = pk2((c.z-mu)*rs*w1.z + b1.z, (c.w-mu)*rs*w1.w + b1.w);
  *(uint4*)((char*)xo + (size_t)r*1024 + l*16) = pk;
}

// ---------------- bf16 MFMA GEMM, 128x128 tile, BK=64 ----------------
// C[r][c] = sum_k A[r][k]*B[c][k]; A,B row-major [*][512] bf16.
// STATMODE: 0 none, 1 per-row-per-head (sum,ss) -> stat, 2 per-col (sum,ss) -> stat
// F32OUT: 0 bf16 out, 1 f32 out + bias
template<int STATMODE, int F32OUT>
__global__ __launch_bounds__(256) void gemm_k(
    const u16* __restrict__ A, const u16* __restrict__ B,
    u16* __restrict__ Cb, float* __restrict__ Cf,
    float* __restrict__ stat, const float* __restrict__ bias, int ldC){
  __shared__ __align__(16) char sA[128*128];
  __shared__ __align__(16) char sB[128*128];
  const int t = threadIdx.x, w = t >> 6, l = t & 63;
  const int wr = w >> 1, wc = w & 1;
  const int lr = l & 15, lg = l >> 4;
  const int row0 = blockIdx.x * 128, col0 = blockIdx.y * 128;
  f32x4 acc[4][4] = {};

  for (int kt = 0; kt < 8; ++kt){
    __syncthreads();
#pragma unroll
    for (int ii = 0; ii < 4; ++ii){
      int c = ii*256 + t, r = c >> 3, k8 = c & 7;
      int so = kt*128 + ((k8*16) ^ ((r & 7) << 4));
      gload16((const char*)A + ((size_t)(row0 + r) << 10) + so, sA + ii*4096 + w*1024);
      gload16((const char*)B + ((size_t)(col0 + r) << 10) + so, sB + ii*4096 + w*1024);
    }
    __syncthreads();
#pragma unroll
    for (int kk = 0; kk < 2; ++kk){
      bf16x8 af[4], bfg[4];
#pragma unroll
      for (int m = 0; m < 4; ++m){
        int r = wr*64 + m*16 + lr;
        af[m] = *(const bf16x8*)(sA + r*128 + ((kk*64 + lg*16) ^ ((lr & 7) << 4)));
      }
#pragma unroll
      for (int n = 0; n < 4; ++n){
        int r = wc*64 + n*16 + lr;
        bfg[n] = *(const bf16x8*)(sB + r*128 + ((kk*64 + lg*16) ^ ((lr & 7) << 4)));
      }
#pragma unroll
      for (int m = 0; m < 4; ++m)
#pragma unroll
        for (int n = 0; n < 4; ++n)
          acc[m][n] = __builtin_amdgcn_mfma_f32_16x16x32_bf16(af[m], bfg[n], acc[m][n], 0, 0, 0);
    }
  }
  // epilogue: D row-in-tile = lg*4+q, col-in-tile = lr
#pragma unroll
  for (int m = 0; m < 4; ++m){
#pragma unroll
    for (int q = 0; q < 4; ++q){
      int r = row0 + wr*64 + m*16 + lg*4 + q;
#pragma unroll
      for (int n = 0; n < 4; ++n){
        int cc = col0 + wc*64 + n*16 + lr;
        float v = acc[m][n][q];
        if (F32OUT) Cf[(size_t)r*ldC + cc] = v + bias[cc];
        else        Cb[(size_t)r*ldC + cc] = f2bf(v);
      }
    }
  }
  if (STATMODE == 1){
    // per-row stats over this wave's 64 cols (= one head)
    int head = (col0 >> 6) + wc;
#pragma unroll
    for (int m = 0; m < 4; ++m){
#pragma unroll
      for (int q = 0; q < 4; ++q){
        float s = 0.f, s2 = 0.f;
#pragma unroll
        for (int n = 0; n < 4; ++n){ float vv = acc[m][n][q]; s += vv; s2 += vv*vv; }
#pragma unroll
        for (int off = 1; off < 16; off <<= 1){ s += __shfl_xor(s, off); s2 += __shfl_xor(s2, off); }
        if (lr == 0){
          int rg = row0 + wr*64 + m*16 + lg*4 + q;
          *(float2*)(stat + ((size_t)rg*8 + head)*2) = make_float2(s, s2);
        }
      }
    }
  }
  if (STATMODE == 2){
    // per-col stats over this wave's 64 rows (= one head)
    int head = (row0 >> 6) + wr;
#pragma unroll
    for (int n = 0; n < 4; ++n){
      float s = 0.f, s2 = 0.f;
#pragma unroll
      for (int m = 0; m < 4; ++m)
#pragma unroll
        for (int q = 0; q < 4; ++q){ float vv = acc[m][n][q]; s += vv; s2 += vv*vv; }
      s += __shfl_xor(s, 16); s2 += __shfl_xor(s2, 16);
      s += __shfl_xor(s, 32); s2 += __shfl_xor(s2, 32);
      if (lg == 0){
        int tok = col0 + wc*64 + n*16 + lr;
        *(float2*)(stat + ((size_t)tok*8 + head)*2) = make_float2(s, s2);
      }
    }
  }
}

// ---------------- attention: per (h,b), factored rank-64 form, MFMA ----------------
// kT,vT: [512 inner][16384 tokens] bf16. fq: [16384][512] bf16.
// qstat/kstat: [16384][8][2] f32 (sum, sumsq per token per head).
__global__ __launch_bounds__(512) void attn_k(
    const u16* __restrict__ fq, const u16* __restrict__ kT, const u16* __restrict__ vT,
    const float* __restrict__ qstat, const float* __restrict__ kstat,
    u16* __restrict__ ao,
    const float* __restrict__ cwr, const float* __restrict__ vwr){
  // LDS: sK [64][1024B] @0 (64K), sV [64][1024B] @65536 (64K),
  //      sStat f32[kin 512 | mk 512 | kv 512 | s1 64 | s2 64] @131072
  //      phase B: sM1 [64][128B] @0, sM2 @8192, sQ [512][128B] @65536
  __shared__ __align__(16) char smem[131072 + 1664*4];
  float* sStat = (float*)(smem + 131072);
  float* sS1 = sStat + 1536;
  float* sS2 = sStat + 1600;

  const int t = threadIdx.x, w = t >> 6, l = t & 63;
  const int lr = l & 15, lg = l >> 4;
  const int h = blockIdx.x & 7, b = blockIdx.x >> 3;

  float cwv = 1.f/(1.f + __expf(-*cwr));
  float vwv = 1.f/(1.f + __expf(-*vwr));
  float cosw = 1.f - cwv - vwv;

  // ---- stage K^T, V^T (swizzled source, linear LDS) ----
  const char* kTb = (const char*)kT + (size_t)h*64*32768 + (size_t)b*1024;
  const char* vTb = (const char*)vT + (size_t)h*64*32768 + (size_t)b*1024;
#pragma unroll
  for (int ii = 0; ii < 8; ++ii){
    int c = ii*512 + t, d = c >> 6, u = c & 63;
    int so = d*32768 + ((u ^ (d & 7)) << 4);
    gload16(kTb + so, smem + ii*8192 + w*1024);
    gload16(vTb + so, smem + 65536 + ii*8192 + w*1024);
  }
  // ---- token stats from kstat (overlaps load latency) ----
  {
    float2 ksr = *(const float2*)(kstat + ((size_t)(b*512 + t)*8 + h)*2);
    float mk = ksr.x * (1.f/64.f);
    sStat[t]        = rsqrtf(ksr.y);
    sStat[512 + t]  = mk;
    sStat[1024 + t] = (ksr.y - 64.f*mk*mk) * (1.f/63.f);
  }
  __syncthreads();

  // ---- phase 1a: M2T[j][i] = sum_m V[m][j]*K[m][i]  (wave: jt=w>>1, it-pair=w&1) ----
  const int jt = (w >> 1), itp = (w & 1);
  f32x4 m2acc[2] = {}, m1acc[2] = {};
  {
    const int j = jt*16 + lr;
#pragma unroll
    for (int ks = 0; ks < 16; ++ks){
      int u = ks*4 + lg;
      bf16x8 af = *(const bf16x8*)(smem + 65536 + j*1024 + ((u ^ (j & 7)) << 4));
#pragma unroll
      for (int tt = 0; tt < 2; ++tt){
        int i = (itp*2 + tt)*16 + lr;
        bf16x8 bf = *(const bf16x8*)(smem + i*1024 + ((u ^ (i & 7)) << 4));
        m2acc[tt] = __builtin_amdgcn_mfma_f32_16x16x32_bf16(af, bf, m2acc[tt], 0, 0, 0);
      }
    }
  }
  // ---- s1/s2: thread (j=t>>3, g=t&7) partial over 64 tokens ----
  {
    int j = t >> 3, g = t & 7;
    float p1 = 0.f, p2 = 0.f;
#pragma unroll
    for (int uu = 0; uu < 8; ++uu){
      int ut = g*8 + uu;
      uint4 uv = *(const uint4*)(smem + 65536 + j*1024 + ((ut ^ (j & 7)) << 4));
      int m0 = ut*8;
      float4 mk0 = *(const float4*)(sStat + 512 + m0);
      float4 mk1 = *(const float4*)(sStat + 512 + m0 + 4);
      float4 kv0 = *(const float4*)(sStat + 1024 + m0);
      float4 kv1 = *(const float4*)(sStat + 1024 + m0 + 4);
      float v0=bflo(uv.x),v1=bfhi(uv.x),v2=bflo(uv.y),v3=bfhi(uv.y);
      float v4=bflo(uv.z),v5=bfhi(uv.z),v6=bflo(uv.w),v7=bfhi(uv.w);
      p1 += v0*mk0.x + v1*mk0.y + v2*mk0.z + v3*mk0.w
          + v4*mk1.x + v5*mk1.y + v6*mk1.z + v7*mk1.w;
      p2 += v0*kv0.x + v1*kv0.y + v2*kv0.z + v3*kv0.w
          + v4*kv1.x + v5*kv1.y + v6*kv1.z + v7*kv1.w;
    }
#pragma unroll
    for (int off = 1; off < 8; off <<= 1){ p1 += __shfl_xor(p1, off); p2 += __shfl_xor(p2, off); }
    if (g == 0){ sS1[j] = p1; sS2[j] = p2; }
  }
  __syncthreads();

  // ---- scale K in place by kin[token] ----
#pragma unroll
  for (int ii = 0; ii < 32; ++ii){
    int wd = ii*512 + t;
    int d = wd >> 8, o = wd & 255, ud = o >> 2, p = o & 3;
    int m0 = ((ud ^ (d & 7)) << 3) + p*2;
    u32 uv = *(u32*)(smem + wd*4);
    *(u32*)(smem + wd*4) = pk2(bflo(uv)*sStat[m0], bfhi(uv)*sStat[m0+1]);
  }
  __syncthreads();

  // ---- phase 1b: M1T[j][i] = sum_m V[m][j]*Ks[m][i] ----
  {
    const int j = jt*16 + lr;
#pragma unroll
    for (int ks = 0; ks < 16; ++ks){
      int u = ks*4 + lg;
      bf16x8 af = *(const bf16x8*)(smem + 65536 + j*1024 + ((u ^ (j & 7)) << 4));
#pragma unroll
      for (int tt = 0; tt < 2; ++tt){
        int i = (itp*2 + tt)*16 + lr;
        bf16x8 bf = *(const bf16x8*)(smem + i*1024 + ((u ^ (i & 7)) << 4));
        m1acc[tt] = __builtin_amdgcn_mfma_f32_16x16x32_bf16(af, bf, m1acc[tt], 0, 0, 0);
      }
    }
  }
  __syncthreads();

  // ---- write M1,M2 (bf16, swizzled) over sK; stage Q over sV ----
#pragma unroll
  for (int tt = 0; tt < 2; ++tt){
#pragma unroll
    for (int q = 0; q < 4; ++q){
      int j = jt*16 + lg*4 + q;
      int i = (itp*2 + tt)*16 + lr;
      int bo = j*128 + (((i >> 3) ^ (j & 7)) << 4) + (i & 7)*2;
      *(u16*)(smem + bo)        = f2bf(m1acc[tt][q]);
      *(u16*)(smem + 8192 + bo) = f2bf(m2acc[tt][q]);
    }
  }
  const char* fqb = (const char*)fq + (size_t)b*524288 + h*128;
#pragma unroll
  for (int ii = 0; ii < 8; ++ii){
    int c = ii*512 + t, n = c >> 3, u = c & 7;
    gload16(fqb + n*1024 + ((u ^ (n & 7)) << 4), smem + 65536 + ii*8192 + w*1024);
  }
  __syncthreads();

  // ---- phase 2: per wave n-slice [w*64, w*64+64) ----
  float s1v[4], s2v[4];
#pragma unroll
  for (int nt = 0; nt < 4; ++nt){ s1v[nt] = sS1[nt*16 + lr]; s2v[nt] = sS2[nt*16 + lr]; }
  const float Bc = cwv * (1.f/64.f);

#pragma unroll
  for (int mt = 0; mt < 4; ++mt){
    f32x4 a1[4] = {}, a2[4] = {};
    const int n = w*64 + mt*16 + lr;
#pragma unroll
    for (int kk = 0; kk < 2; ++kk){
      int u = kk*4 + lg;
      bf16x8 af = *(const bf16x8*)(smem + 65536 + n*128 + ((u ^ (n & 7)) << 4));
#pragma unroll
      for (int nt = 0; nt < 4; ++nt){
        int j = nt*16 + lr;
        bf16x8 b1 = *(const bf16x8*)(smem + j*128 + ((u ^ (j & 7)) << 4));
        bf16x8 b2 = *(const bf16x8*)(smem + 8192 + j*128 + ((u ^ (j & 7)) << 4));
        a1[nt] = __builtin_amdgcn_mfma_f32_16x16x32_bf16(af, b1, a1[nt], 0, 0, 0);
        a2[nt] = __builtin_amdgcn_mfma_f32_16x16x32_bf16(af, b2, a2[nt], 0, 0, 0);
      }
    }
#pragma unroll
    for (int q = 0; q < 4; ++q){
      int nr = w*64 + mt*16 + lg*4 + q;
      float2 qs = *(const float2*)(qstat + ((size_t)(b*512 + nr)*8 + h)*2);
      float mq = qs.x * (1.f/64.f);
      float An = cosw * rsqrtf(qs.y);
      float Cn = -cwv * mq;
      float En = vwv * (1.f/64.f) * ((qs.y - 64.f*mq*mq) * (1.f/63.f));
      char* op = (char*)ao + ((size_t)(b*512 + nr)*512 + h*64)*2;
#pragma unroll
      for (int nt = 0; nt < 4; ++nt){
        float ov = An*a1[nt][q] + Bc*a2[nt][q] + Cn*s1v[nt] + En*s2v[nt];
        *(u16*)(op + (nt*16 + lr)*2) = f2bf(ov);
      }
    }
  }
}

// ---------------- launch ----------------
extern "C" void kernel_launch(void* const* d_in, const int* in_sizes, int n_in,
                              void* d_out, int out_size, void* d_ws, size_t ws_size,
                              hipStream_t stream){
  const float* q    = (const float*)d_in[0];
  const float* k    = (const float*)d_in[1];
  const float* v    = (const float*)d_in[2];
  const float* lnw  = (const float*)d_in[3];
  const float* lnb  = (const float*)d_in[4];
  const float* Win  = (const float*)d_in[5];
  const float* Wout = (const float*)d_in[6];
  const float* bout = (const float*)d_in[7];
  const float* cwr  = (const float*)d_in[8];
  const float* vwr  = (const float*)d_in[9];

  char* ws = (char*)d_ws;
  const size_t FB = (size_t)16384 * 512 * 2;   // 16 MiB bf16 buffer
  u16* xnq = (u16*)(ws);
  u16* xnk = (u16*)(ws + FB);
  u16* xnv = (u16*)(ws + 2*FB);
  u16* fq  = (u16*)(ws + 3*FB);
  u16* kT  = (u16*)(ws);          // overlays xnq (consumed by then)
  u16* vT  = (u16*)(ws + FB);     // overlays xnk
  u16* ao  = (u16*)(ws + 2*FB);   // overlays xnv
  u16* WinT  = (u16*)(ws + 4*FB);
  u16* WoutT = (u16*)(ws + 4*FB + 524288);
  // stats scratch in d_out (dead before final GEMM writes it)
  float* qstat = (float*)d_out;
  float* kstat = qstat + 262144;

  transw_k<<<dim3(16,16,2), 256, 0, stream>>>(Win, Wout, WinT, WoutT);
  lnx_k<<<12288, 256, 0, stream>>>(q, k, v, lnw, lnb, xnq, xnk, xnv);

  // Q: normal orientation, row(=token) stats
  gemm_k<1,0><<<dim3(128,4), 256, 0, stream>>>(xnq, WinT, fq, nullptr, qstat, nullptr, 512);
  // K: transposed orientation (C[inner][token]), col(=token) stats
  gemm_k<2,0><<<dim3(4,128), 256, 0, stream>>>(WinT, xnk, kT, nullptr, kstat, nullptr, 16384);
  // V: transposed orientation, no stats
  gemm_k<0,0><<<dim3(4,128), 256, 0, stream>>>(WinT, xnv, vT, nullptr, nullptr, nullptr, 16384);

  attn_k<<<256, 512, 0, stream>>>(fq, kT, vT, qstat, kstat, ao, cwr, vwr);

  // out = ao @ Wout + bias (f32)
  gemm_k<0,1><<<dim3(128,4), 256, 0, stream>>>(ao, WoutT, nullptr, (float*)d_out, nullptr, bout, 512);
}